// Round 2
// baseline (309.696 us; speedup 1.0000x reference)
//
#include <hip/hip_runtime.h>
#include <hip/hip_bf16.h>

#define TDIM 8192
#define BDIM 16
#define HDIM 256
#define PHL  513
#define PADL 515
#define MROWS (BDIM*PHL)   // 8208
#define SEGW 514

typedef __attribute__((ext_vector_type(8))) short  short8;
typedef __attribute__((ext_vector_type(4))) float  floatx4;

__device__ __forceinline__ float sigmoidf_(float x){ return 1.0f/(1.0f+__expf(-x)); }

// async global->LDS, 16B per lane; dest = lds base (wave-uniform) + lane*16
typedef __attribute__((address_space(1))) const unsigned int gu32;
typedef __attribute__((address_space(3))) unsigned int lu32;
__device__ __forceinline__ void g2l16(const void* g, void* l){
  __builtin_amdgcn_global_load_lds((gu32*)g, (lu32*)l, 16, 0, 0);
}

__device__ __forceinline__ float blk_reduce(float v, float* red){
  #pragma unroll
  for (int off=32; off>0; off>>=1) v += __shfl_xor(v, off, 64);
  int w = threadIdx.x>>6;
  __syncthreads();
  if ((threadIdx.x&63)==0) red[w]=v;
  __syncthreads();
  return red[0]+red[1]+red[2]+red[3];
}

// ---------------- K0: scan ph_bd -> seg_start table [B][514] ----------------------
__global__ __launch_bounds__(256) void k_scan(const int* __restrict__ ph_bd,
                                              int* __restrict__ seg){
  int b = blockIdx.x, tid = threadIdx.x;
  const int* in = ph_bd + (size_t)b*TDIM;
  int sb = b*SEGW;
  int base = tid*32;
  int vals[32]; int s=0;
  #pragma unroll
  for (int i=0;i<32;i+=4){
    int4 v = *(const int4*)(in+base+i);
    vals[i]=v.x; vals[i+1]=v.y; vals[i+2]=v.z; vals[i+3]=v.w;
    s += v.x+v.y+v.z+v.w;
  }
  __shared__ int ls[256];
  ls[tid]=s; __syncthreads();
  for (int off=1; off<256; off<<=1){
    int t = (tid>=off)? ls[tid-off] : 0;
    __syncthreads();
    ls[tid]+=t;
    __syncthreads();
  }
  int cur = ls[tid]-s;                    // m2p before this thread's range
  #pragma unroll
  for (int i=0;i<32;i++){
    int nxt = cur + vals[i];
    for (int v=cur+1; v<=nxt; v++) seg[sb+v] = base+i;   // seg_start[v]=min t: m2p[t]>=v
    cur = nxt;
  }
  if (tid==0) seg[sb] = 0;
  if (tid==255){ for (int v=cur+1; v<SEGW; v++) seg[sb+v] = TDIM; }
}

// ---------------- K_prep: bf16 weight transposes, rowoff, zero pad rows -----------
__global__ __launch_bounds__(256) void k_prep(
    const float* __restrict__ conv1_w, const float* __restrict__ conv2_w,
    const float* __restrict__ post_w,
    __bf16* __restrict__ w1t, __bf16* __restrict__ w2t, __bf16* __restrict__ w3t,
    int* __restrict__ rowoff,
    float* __restrict__ x0pad, __bf16* __restrict__ h1pad, __bf16* __restrict__ x2pad)
{
  int idx = blockIdx.x*256 + threadIdx.x;
  if (idx < 256*768){                       // [o][k=dl*256+i]
    int o = idx/768, j = idx - o*768;
    int dl = j>>8, i = j&255;
    int src = (o*256+i)*3 + dl;
    w1t[idx] = (__bf16)conv1_w[src];
    w3t[idx] = (__bf16)post_w[src];
  }
  if (idx < 256*256)
    w2t[idx] = (__bf16)conv2_w[idx];
  if (idx < MROWS){
    int b = idx/513, l = idx - b*513;
    rowoff[idx] = (b*PADL + l)*HDIM;        // conv-window start (padded row l == data row l-1)
  }
  if (idx < BDIM*2*HDIM){                   // zero pad rows (ws is poisoned)
    int b = idx>>9, rr=(idx>>8)&1, c=idx&255;
    size_t row = (size_t)b*PADL + (rr? (PADL-1):0);
    x0pad[row*HDIM+c]=0.f;
    h1pad[row*HDIM+c]=(__bf16)0.f;
    x2pad[row*HDIM+c]=(__bf16)0.f;
  }
}

// ---------------- K1: attn + segment aggregation + nonpad + LN1 (float4) ----------
__global__ __launch_bounds__(256) void k_attn(
    const float* __restrict__ feat, const int* __restrict__ seg,
    const float* __restrict__ w_attn, const float* __restrict__ b_attn,
    const float* __restrict__ ln1_g, const float* __restrict__ ln1_b,
    float* __restrict__ x0pad, __bf16* __restrict__ h1pad, float* __restrict__ nonpad)
{
  int b = blockIdx.x / PHL, p = blockIdx.x - b*PHL;
  int tid = threadIdx.x, lane = tid&63, w = tid>>6;
  __shared__ float4 sfeat[16*64];           // [frame][lane-group] 16 KB
  __shared__ float sam[16];
  __shared__ float red[4];

  int t0 = seg[b*SEGW + p], t1 = seg[b*SEGW + p + 1];

  float4 wa0 = ((const float4*)w_attn)[lane];
  float4 wa1 = ((const float4*)(w_attn+HDIM))[lane];
  float ba0 = b_attn[0], ba1 = b_attn[1];

  float agg=0.f, denom=0.f;
  for (int base=t0; base<t1; base+=16){
    int nf = min(16, t1-base);
    const float4* src = (const float4*)(feat + ((size_t)b*TDIM + base)*HDIM);
    for (int idx=tid; idx<nf*64; idx+=256) sfeat[idx] = src[idx];
    __syncthreads();
    for (int ft=w; ft<nf; ft+=4){
      float4 f = sfeat[ft*64+lane];
      float d0 = f.x*wa0.x + f.y*wa0.y + f.z*wa0.z + f.w*wa0.w;
      float d1 = f.x*wa1.x + f.y*wa1.y + f.z*wa1.z + f.w*wa1.w;
      #pragma unroll
      for (int off=32;off>0;off>>=1){ d0+=__shfl_xor(d0,off,64); d1+=__shfl_xor(d1,off,64); }
      if (lane==0) sam[ft] = 0.5f*(sigmoidf_(d0+ba0)+sigmoidf_(d1+ba1));
    }
    __syncthreads();
    const float* sf = (const float*)sfeat;
    for (int ft=0; ft<nf; ft++){ float a=sam[ft]; agg += sf[ft*HDIM+tid]*a; denom += a; }
    __syncthreads();
  }

  float x = agg/(denom+1e-5f);
  float sabs = blk_reduce(fabsf(x), red);
  float np = (sabs>0.f)?1.f:0.f;
  float mean = blk_reduce(x, red)*(1.f/HDIM);
  float d = x-mean;
  float var = blk_reduce(d*d, red)*(1.f/HDIM);
  float h = d*rsqrtf(var+1e-5f)*ln1_g[tid]+ln1_b[tid];

  size_t off = ((size_t)b*PADL + p + 1)*HDIM;
  x0pad[off+tid]=x;
  h1pad[off+tid]=(__bf16)h;
  if (tid==0) nonpad[blockIdx.x]=np;
}

// ---------------- K2: fused conv1+silu+conv2+residual+LN2 -------------------------
// block = 64 rows x 256 cols; 4 waves, wave w owns rows [w*16, w*16+16)
__global__ __launch_bounds__(256) void k_convblock(
    const short* __restrict__ h1pad, const int* __restrict__ rowoff,
    const short* __restrict__ w1t, const short* __restrict__ w2t,
    const float* __restrict__ c1b, const float* __restrict__ c2b,
    const float* __restrict__ x0pad, const float* __restrict__ nonpad,
    const float* __restrict__ g2, const float* __restrict__ b2,
    __bf16* __restrict__ x2pad)
{
  __shared__ __align__(16) short As[4*64*8];    // [kq][m][8]  4 KB
  __shared__ __align__(16) short Bs[4*256*8];   // [kq][n][8] 16 KB
  __shared__ __align__(16) short Gt[32*64*8];   // g tile, [kq][m][8] K=256, 32 KB
  int tid=threadIdx.x, lane=tid&63, w=tid>>6, quad=lane>>4, l15=lane&15;
  int m0 = blockIdx.x*64;
  int am = min(m0 + lane, MROWS-1);
  const short* aRow = h1pad + rowoff[am];       // 768-wide im2col window
  short* AsW = &As[w*64*8];                     // wave-uniform dest base

  floatx4 acc[16];
  #pragma unroll
  for (int i=0;i<16;i++) acc[i] = (floatx4){0.f,0.f,0.f,0.f};

  // ---- GEMM1: h1 @ w1t (K=768) ----
  for (int chunk=0; chunk<24; chunk++){
    int k0 = chunk*32;
    g2l16(aRow + k0 + w*8, AsW);
    #pragma unroll
    for (int ng=0; ng<4; ng++)
      g2l16(w1t + (size_t)(ng*64+lane)*768 + k0 + w*8, &Bs[(w*256 + ng*64)*8]);
    __syncthreads();
    short8 af = *(const short8*)&As[(quad*64 + w*16 + l15)*8];
    #pragma unroll
    for (int nt=0; nt<16; nt++){
      short8 bf = *(const short8*)&Bs[(quad*256 + nt*16 + l15)*8];
      acc[nt] = __builtin_amdgcn_mfma_f32_16x16x32_bf16(af, bf, acc[nt], 0,0,0);
    }
    __syncthreads();
  }

  // epilogue 1: bias, *3^-0.5, silu -> Gt (wave-private rows)
  const float inv_s3 = 0.57735026918962576f;
  #pragma unroll
  for (int nt=0; nt<16; nt++){
    int n = nt*16 + l15;
    float bias = c1b[n];
    #pragma unroll
    for (int r=0;r<4;r++){
      float v = (acc[nt][r] + bias)*inv_s3;
      v = v*sigmoidf_(v);
      int ml = w*16 + quad*4 + r;
      ((__bf16*)Gt)[((n>>3)*64 + ml)*8 + (n&7)] = (__bf16)v;
    }
  }

  // ---- GEMM2: g @ w2t (K=256), A-frags straight from Gt ----
  floatx4 acc2[16];
  #pragma unroll
  for (int i=0;i<16;i++) acc2[i] = (floatx4){0.f,0.f,0.f,0.f};
  for (int chunk=0; chunk<8; chunk++){
    int k0 = chunk*32;
    #pragma unroll
    for (int ng=0; ng<4; ng++)
      g2l16(w2t + (size_t)(ng*64+lane)*256 + k0 + w*8, &Bs[(w*256 + ng*64)*8]);
    __syncthreads();
    short8 af = *(const short8*)&Gt[((chunk*4+quad)*64 + w*16 + l15)*8];
    #pragma unroll
    for (int nt=0; nt<16; nt++){
      short8 bf = *(const short8*)&Bs[(quad*256 + nt*16 + l15)*8];
      acc2[nt] = __builtin_amdgcn_mfma_f32_16x16x32_bf16(af, bf, acc2[nt], 0,0,0);
    }
    __syncthreads();
  }

  // epilogue 2: x=(x0+h2)*np, LN over 256 channels (row lives in 16 lanes), ->x2pad
  int mbase = m0 + w*16 + quad*4;
  float np_[4]; const float* x0b[4]; int roff[4];
  #pragma unroll
  for (int r=0;r<4;r++){
    int m = min(mbase + r, MROWS-1);
    np_[r] = nonpad[m];
    roff[r] = rowoff[m] + HDIM;               // data row in padded layout
    x0b[r] = x0pad + roff[r];
  }
  float sum[4]={0,0,0,0}, ssq[4]={0,0,0,0};
  #pragma unroll
  for (int nt=0; nt<16; nt++){
    int n = nt*16 + l15;
    float cb = c2b[n];
    #pragma unroll
    for (int r=0;r<4;r++){
      float x = (x0b[r][n] + acc2[nt][r] + cb)*np_[r];
      acc2[nt][r] = x;
      sum[r]+=x; ssq[r]+=x*x;
    }
  }
  #pragma unroll
  for (int off=1; off<16; off<<=1){
    #pragma unroll
    for (int r=0;r<4;r++){ sum[r]+=__shfl_xor(sum[r],off,64); ssq[r]+=__shfl_xor(ssq[r],off,64); }
  }
  float mean[4], rs[4];
  #pragma unroll
  for (int r=0;r<4;r++){
    mean[r]=sum[r]*(1.f/HDIM);
    float var=ssq[r]*(1.f/HDIM)-mean[r]*mean[r];
    rs[r]=rsqrtf(var+1e-5f);
  }
  #pragma unroll
  for (int nt=0; nt<16; nt++){
    int n = nt*16 + l15;
    float gg=g2[n], bb=b2[n];
    #pragma unroll
    for (int r=0;r<4;r++){
      int m = mbase + r;
      if (m < MROWS){
        float y = ((acc2[nt][r]-mean[r])*rs[r]*gg + bb)*np_[r];
        x2pad[roff[r]+n] = (__bf16)y;
      }
    }
  }
}

// ---------------- K3: fused post-conv (K=768) + nonpad + logits -> d_out ----------
__global__ __launch_bounds__(256) void k_post(
    const short* __restrict__ x2pad, const int* __restrict__ rowoff,
    const short* __restrict__ w3t, const float* __restrict__ postb,
    const float* __restrict__ nonpad, const float* __restrict__ w_out,
    const float* __restrict__ b_out, float* __restrict__ dst)
{
  __shared__ __align__(16) short As[4*64*8];
  __shared__ __align__(16) short Bs[4*256*8];
  __shared__ float ws[5*256];
  int tid=threadIdx.x, lane=tid&63, w=tid>>6, quad=lane>>4, l15=lane&15;
  int m0 = blockIdx.x*64;
  int am = min(m0 + lane, MROWS-1);
  const short* aRow = x2pad + rowoff[am];
  short* AsW = &As[w*64*8];
  for (int i=tid; i<5*256; i+=256) ws[i]=w_out[i];

  floatx4 acc[16];
  #pragma unroll
  for (int i=0;i<16;i++) acc[i] = (floatx4){0.f,0.f,0.f,0.f};
  for (int chunk=0; chunk<24; chunk++){
    int k0 = chunk*32;
    g2l16(aRow + k0 + w*8, AsW);
    #pragma unroll
    for (int ng=0; ng<4; ng++)
      g2l16(w3t + (size_t)(ng*64+lane)*768 + k0 + w*8, &Bs[(w*256 + ng*64)*8]);
    __syncthreads();
    short8 af = *(const short8*)&As[(quad*64 + w*16 + l15)*8];
    #pragma unroll
    for (int nt=0; nt<16; nt++){
      short8 bf = *(const short8*)&Bs[(quad*256 + nt*16 + l15)*8];
      acc[nt] = __builtin_amdgcn_mfma_f32_16x16x32_bf16(af, bf, acc[nt], 0,0,0);
    }
    __syncthreads();
  }

  int mbase = m0 + w*16 + quad*4;
  float np_[4];
  #pragma unroll
  for (int r=0;r<4;r++) np_[r] = nonpad[min(mbase+r, MROWS-1)];
  float p[4][5];
  #pragma unroll
  for (int r=0;r<4;r++)
    #pragma unroll
    for (int o=0;o<5;o++) p[r][o]=0.f;
  #pragma unroll
  for (int nt=0; nt<16; nt++){
    int n = nt*16 + l15;
    float pb = postb[n];
    float wv[5];
    #pragma unroll
    for (int o=0;o<5;o++) wv[o]=ws[o*256+n];
    #pragma unroll
    for (int r=0;r<4;r++){
      float v = (acc[nt][r] + pb)*np_[r];
      #pragma unroll
      for (int o=0;o<5;o++) p[r][o] += v*wv[o];
    }
  }
  #pragma unroll
  for (int off=1; off<16; off<<=1)
    #pragma unroll
    for (int r=0;r<4;r++)
      #pragma unroll
      for (int o=0;o<5;o++) p[r][o]+=__shfl_xor(p[r][o],off,64);
  if (l15==0){
    #pragma unroll
    for (int r=0;r<4;r++){
      int m = mbase + r;
      if (m < MROWS){
        #pragma unroll
        for (int o=0;o<5;o++) dst[(size_t)m*5+o] = p[r][o] + b_out[o];
      }
    }
  }
}

extern "C" void kernel_launch(void* const* d_in, const int* in_sizes, int n_in,
                              void* d_out, int out_size, void* d_ws, size_t ws_size,
                              hipStream_t stream) {
  const float* feat    = (const float*)d_in[0];
  const int*   ph_bd   = (const int*)  d_in[1];
  const float* w_attn  = (const float*)d_in[3];
  const float* b_attn  = (const float*)d_in[4];
  const float* ln1_g   = (const float*)d_in[5];
  const float* ln1_b   = (const float*)d_in[6];
  const float* conv1_w = (const float*)d_in[7];
  const float* conv1_b = (const float*)d_in[8];
  const float* conv2_w = (const float*)d_in[9];
  const float* conv2_b = (const float*)d_in[10];
  const float* ln2_g   = (const float*)d_in[11];
  const float* ln2_b   = (const float*)d_in[12];
  const float* post_w  = (const float*)d_in[13];
  const float* post_b  = (const float*)d_in[14];
  const float* w_out   = (const float*)d_in[15];
  const float* b_out   = (const float*)d_in[16];

  char* wp = (char*)d_ws;
  auto alloc = [&](size_t bytes)->void*{
    void* p = (void*)wp; wp += (bytes + 255) & ~(size_t)255; return p;
  };
  int*    seg    = (int*)   alloc((size_t)BDIM*SEGW*4);
  int*    rowoff = (int*)   alloc((size_t)MROWS*4);
  float*  x0pad  = (float*) alloc((size_t)BDIM*PADL*HDIM*4);
  __bf16* h1pad  = (__bf16*)alloc((size_t)BDIM*PADL*HDIM*2);
  __bf16* x2pad  = (__bf16*)alloc((size_t)BDIM*PADL*HDIM*2);
  float*  nonpad = (float*) alloc((size_t)MROWS*4);
  __bf16* w1t    = (__bf16*)alloc((size_t)256*768*2);
  __bf16* w2t    = (__bf16*)alloc((size_t)256*256*2);
  __bf16* w3t    = (__bf16*)alloc((size_t)256*768*2);

  k_scan<<<BDIM, 256, 0, stream>>>(ph_bd, seg);
  k_prep<<<768, 256, 0, stream>>>(conv1_w, conv2_w, post_w, w1t, w2t, w3t,
                                  rowoff, x0pad, h1pad, x2pad);
  k_attn<<<MROWS, 256, 0, stream>>>(feat, seg, w_attn, b_attn,
                                    ln1_g, ln1_b, x0pad, h1pad, nonpad);
  k_convblock<<<129, 256, 0, stream>>>((const short*)h1pad, rowoff, (const short*)w1t,
                                       (const short*)w2t, conv1_b, conv2_b,
                                       x0pad, nonpad, ln2_g, ln2_b, x2pad);
  k_post<<<129, 256, 0, stream>>>((const short*)x2pad, rowoff, (const short*)w3t,
                                  post_b, nonpad, w_out, b_out, (float*)d_out);
}

// Round 3
// 301.826 us; speedup vs baseline: 1.0261x; 1.0261x over previous
//
#include <hip/hip_runtime.h>
#include <hip/hip_bf16.h>

#define TDIM 8192
#define BDIM 16
#define HDIM 256
#define PHL  513
#define PADL 515
#define MROWS (BDIM*PHL)   // 8208
#define SEGW 514

typedef __attribute__((ext_vector_type(8))) short  short8;
typedef __attribute__((ext_vector_type(4))) float  floatx4;

__device__ __forceinline__ float sigmoidf_(float x){ return 1.0f/(1.0f+__expf(-x)); }

// async global->LDS, 16B/lane; dest = wave-uniform LDS base + lane*16
typedef __attribute__((address_space(1))) const unsigned int gu32;
typedef __attribute__((address_space(3))) unsigned int lu32;
__device__ __forceinline__ void g2l16(const void* g, void* l){
  __builtin_amdgcn_global_load_lds((gu32*)g, (lu32*)l, 16, 0, 0);
}

__device__ __forceinline__ float blk_reduce(float v, float* red){
  #pragma unroll
  for (int off=32; off>0; off>>=1) v += __shfl_xor(v, off, 64);
  int w = threadIdx.x>>6;
  __syncthreads();
  if ((threadIdx.x&63)==0) red[w]=v;
  __syncthreads();
  return red[0]+red[1]+red[2]+red[3];
}

// ---------------- K_init: blocks 0..15 = scan(ph_bd->seg); rest = prep -----------
__global__ __launch_bounds__(256) void k_init(
    const int* __restrict__ ph_bd, int* __restrict__ seg,
    const float* __restrict__ conv1_w, const float* __restrict__ conv2_w,
    const float* __restrict__ post_w,
    __bf16* __restrict__ w1t, __bf16* __restrict__ w2t, __bf16* __restrict__ w3t,
    int* __restrict__ rowoff,
    float* __restrict__ x0pad, __bf16* __restrict__ h1pad, __bf16* __restrict__ x2pad)
{
  int tid = threadIdx.x;
  if (blockIdx.x < BDIM){
    int b = blockIdx.x;
    const int* in = ph_bd + (size_t)b*TDIM;
    int sb = b*SEGW;
    int base = tid*32;
    int vals[32]; int s=0;
    #pragma unroll
    for (int i=0;i<32;i+=4){
      int4 v = *(const int4*)(in+base+i);
      vals[i]=v.x; vals[i+1]=v.y; vals[i+2]=v.z; vals[i+3]=v.w;
      s += v.x+v.y+v.z+v.w;
    }
    __shared__ int ls[256];
    ls[tid]=s; __syncthreads();
    for (int off=1; off<256; off<<=1){
      int t = (tid>=off)? ls[tid-off] : 0;
      __syncthreads();
      ls[tid]+=t;
      __syncthreads();
    }
    int cur = ls[tid]-s;
    #pragma unroll
    for (int i=0;i<32;i++){
      int nxt = cur + vals[i];
      for (int v=cur+1; v<=nxt; v++) seg[sb+v] = base+i;
      cur = nxt;
    }
    if (tid==0) seg[sb] = 0;
    if (tid==255){ for (int v=cur+1; v<SEGW; v++) seg[sb+v] = TDIM; }
    return;
  }
  int idx = (blockIdx.x-BDIM)*256 + tid;
  if (idx < 256*768){                       // [o][k=dl*256+i]
    int o = idx/768, j = idx - o*768;
    int dl = j>>8, i = j&255;
    int src = (o*256+i)*3 + dl;
    w1t[idx] = (__bf16)conv1_w[src];
    w3t[idx] = (__bf16)post_w[src];
  }
  if (idx < 256*256)
    w2t[idx] = (__bf16)conv2_w[idx];
  if (idx < MROWS){
    int b = idx/513, l = idx - b*513;
    rowoff[idx] = (b*PADL + l)*HDIM;
  }
  if (idx < BDIM*2*HDIM){                   // zero pad rows (ws is poisoned)
    int b = idx>>9, rr=(idx>>8)&1, c=idx&255;
    size_t row = (size_t)b*PADL + (rr? (PADL-1):0);
    x0pad[row*HDIM+c]=0.f;
    h1pad[row*HDIM+c]=(__bf16)0.f;
    x2pad[row*HDIM+c]=(__bf16)0.f;
  }
}

// ---------------- K1: attn + segment aggregation + nonpad + LN1 -------------------
__global__ __launch_bounds__(256) void k_attn(
    const float* __restrict__ feat, const int* __restrict__ seg,
    const float* __restrict__ w_attn, const float* __restrict__ b_attn,
    const float* __restrict__ ln1_g, const float* __restrict__ ln1_b,
    float* __restrict__ x0pad, __bf16* __restrict__ h1pad, float* __restrict__ nonpad)
{
  int b = blockIdx.x / PHL, p = blockIdx.x - b*PHL;
  int tid = threadIdx.x, lane = tid&63, w = tid>>6;
  __shared__ float4 sfeat[16*64];
  __shared__ float sam[16];
  __shared__ float red[4];

  int t0 = seg[b*SEGW + p], t1 = seg[b*SEGW + p + 1];

  float4 wa0 = ((const float4*)w_attn)[lane];
  float4 wa1 = ((const float4*)(w_attn+HDIM))[lane];
  float ba0 = b_attn[0], ba1 = b_attn[1];

  float agg=0.f, denom=0.f;
  for (int base=t0; base<t1; base+=16){
    int nf = min(16, t1-base);
    const float4* src = (const float4*)(feat + ((size_t)b*TDIM + base)*HDIM);
    for (int idx=tid; idx<nf*64; idx+=256) sfeat[idx] = src[idx];
    __syncthreads();
    for (int ft=w; ft<nf; ft+=4){
      float4 f = sfeat[ft*64+lane];
      float d0 = f.x*wa0.x + f.y*wa0.y + f.z*wa0.z + f.w*wa0.w;
      float d1 = f.x*wa1.x + f.y*wa1.y + f.z*wa1.z + f.w*wa1.w;
      #pragma unroll
      for (int off=32;off>0;off>>=1){ d0+=__shfl_xor(d0,off,64); d1+=__shfl_xor(d1,off,64); }
      if (lane==0) sam[ft] = 0.5f*(sigmoidf_(d0+ba0)+sigmoidf_(d1+ba1));
    }
    __syncthreads();
    const float* sf = (const float*)sfeat;
    for (int ft=0; ft<nf; ft++){ float a=sam[ft]; agg += sf[ft*HDIM+tid]*a; denom += a; }
    __syncthreads();
  }

  float x = agg/(denom+1e-5f);
  float sabs = blk_reduce(fabsf(x), red);
  float np = (sabs>0.f)?1.f:0.f;
  float mean = blk_reduce(x, red)*(1.f/HDIM);
  float d = x-mean;
  float var = blk_reduce(d*d, red)*(1.f/HDIM);
  float h = d*rsqrtf(var+1e-5f)*ln1_g[tid]+ln1_b[tid];

  size_t off = ((size_t)b*PADL + p + 1)*HDIM;
  x0pad[off+tid]=x;
  h1pad[off+tid]=(__bf16)h;
  if (tid==0) nonpad[blockIdx.x]=np;
}

// ---------------- K2: fused conv1+silu+conv2+residual+LN2 -------------------------
// block = 32 rows x 256 cols; wave w: rows (w>>1)*16.., cols (w&1)*128..
__global__ __launch_bounds__(256) void k_convblock(
    const short* __restrict__ h1pad, const int* __restrict__ rowoff,
    const short* __restrict__ w1t, const short* __restrict__ w2t,
    const float* __restrict__ c1b, const float* __restrict__ c2b,
    const float* __restrict__ x0pad, const float* __restrict__ nonpad,
    const float* __restrict__ g2, const float* __restrict__ b2,
    __bf16* __restrict__ x2pad)
{
  __shared__ __align__(16) short As[4*32*8];    //  2 KB [kq][m32][8]
  __shared__ __align__(16) short Bs[4*256*8];   // 16 KB [kq][n256][8]
  __shared__ __align__(16) short Gt[32*32*8];   // 16 KB [kq32][m32][8]
  __shared__ float s_sum[4][16], s_ssq[4][16];
  int tid=threadIdx.x, lane=tid&63, w=tid>>6, quad=lane>>4, l15=lane&15;
  int g = w>>1, n0w = (w&1)*128;
  int m0 = blockIdx.x*32;
  int arow = min(m0 + (lane&31), MROWS-1);
  const short* aPtr = h1pad + rowoff[arow] + (2*w + (lane>>5))*8;   // used by waves 0,1

  floatx4 acc[8];
  #pragma unroll
  for (int i=0;i<8;i++) acc[i] = (floatx4){0.f,0.f,0.f,0.f};

  // ---- GEMM1: h1 @ w1t (K=768) ----
  for (int chunk=0; chunk<24; chunk++){
    int k0 = chunk*32;
    if (w < 2) g2l16(aPtr + k0, &As[w*64*8]);           // wave-uniform branch
    #pragma unroll
    for (int ng=0; ng<4; ng++)
      g2l16(w1t + (size_t)(ng*64+lane)*768 + k0 + w*8, &Bs[(w*256 + ng*64)*8]);
    __syncthreads();
    short8 af = *(const short8*)&As[(quad*32 + g*16 + l15)*8];
    #pragma unroll
    for (int nt=0; nt<8; nt++){
      short8 bf = *(const short8*)&Bs[(quad*256 + n0w + nt*16 + l15)*8];
      acc[nt] = __builtin_amdgcn_mfma_f32_16x16x32_bf16(af, bf, acc[nt], 0,0,0);
    }
    __syncthreads();
  }

  // epilogue 1 -> Gt (cross-wave rows; barrier before GEMM2 reads orders it)
  const float inv_s3 = 0.57735026918962576f;
  #pragma unroll
  for (int nt=0; nt<8; nt++){
    int n = n0w + nt*16 + l15;
    float bias = c1b[n];
    #pragma unroll
    for (int r=0;r<4;r++){
      float v = (acc[nt][r] + bias)*inv_s3;
      v = v*sigmoidf_(v);
      int m = g*16 + quad*4 + r;
      ((__bf16*)Gt)[((n>>3)*32 + m)*8 + (n&7)] = (__bf16)v;
    }
  }

  // ---- GEMM2: g @ w2t (K=256) ----
  floatx4 acc2[8];
  #pragma unroll
  for (int i=0;i<8;i++) acc2[i] = (floatx4){0.f,0.f,0.f,0.f};
  for (int chunk=0; chunk<8; chunk++){
    int k0 = chunk*32;
    #pragma unroll
    for (int ng=0; ng<4; ng++)
      g2l16(w2t + (size_t)(ng*64+lane)*256 + k0 + w*8, &Bs[(w*256 + ng*64)*8]);
    __syncthreads();
    short8 af = *(const short8*)&Gt[((chunk*4+quad)*32 + g*16 + l15)*8];
    #pragma unroll
    for (int nt=0; nt<8; nt++){
      short8 bf = *(const short8*)&Bs[(quad*256 + n0w + nt*16 + l15)*8];
      acc2[nt] = __builtin_amdgcn_mfma_f32_16x16x32_bf16(af, bf, acc2[nt], 0,0,0);
    }
    __syncthreads();
  }

  // epilogue 2: x=(x0+h2)*np, LN over 256 cols (split across wave pair) -> x2pad
  int mbase = m0 + g*16 + quad*4;
  float np_[4]; int roff[4];
  #pragma unroll
  for (int r=0;r<4;r++){
    int mm = min(mbase + r, MROWS-1);
    np_[r] = nonpad[mm];
    roff[r] = rowoff[mm] + HDIM;
  }
  float sum[4]={0,0,0,0}, ssq[4]={0,0,0,0};
  #pragma unroll
  for (int nt=0; nt<8; nt++){
    int n = n0w + nt*16 + l15;
    float cb = c2b[n];
    #pragma unroll
    for (int r=0;r<4;r++){
      float x = (x0pad[roff[r]+n] + acc2[nt][r] + cb)*np_[r];
      acc2[nt][r] = x;
      sum[r]+=x; ssq[r]+=x*x;
    }
  }
  #pragma unroll
  for (int off=1; off<16; off<<=1){
    #pragma unroll
    for (int r=0;r<4;r++){ sum[r]+=__shfl_xor(sum[r],off,64); ssq[r]+=__shfl_xor(ssq[r],off,64); }
  }
  if (l15==0){
    #pragma unroll
    for (int r=0;r<4;r++){ s_sum[w][quad*4+r]=sum[r]; s_ssq[w][quad*4+r]=ssq[r]; }
  }
  __syncthreads();
  float mean[4], rs[4];
  #pragma unroll
  for (int r=0;r<4;r++){
    int i = quad*4+r;
    float ts = s_sum[w&~1][i] + s_sum[w|1][i];
    float tq = s_ssq[w&~1][i] + s_ssq[w|1][i];
    mean[r] = ts*(1.f/HDIM);
    float var = tq*(1.f/HDIM) - mean[r]*mean[r];
    rs[r] = rsqrtf(var+1e-5f);
  }
  #pragma unroll
  for (int nt=0; nt<8; nt++){
    int n = n0w + nt*16 + l15;
    float gg=g2[n], bb=b2[n];
    #pragma unroll
    for (int r=0;r<4;r++){
      if (mbase + r < MROWS){
        float y = ((acc2[nt][r]-mean[r])*rs[r]*gg + bb)*np_[r];
        x2pad[roff[r]+n] = (__bf16)y;
      }
    }
  }
}

// ---------------- K3: fused post-conv (K=768) + nonpad + logits -> d_out ----------
__global__ __launch_bounds__(256) void k_post(
    const short* __restrict__ x2pad, const int* __restrict__ rowoff,
    const short* __restrict__ w3t, const float* __restrict__ postb,
    const float* __restrict__ nonpad, const float* __restrict__ w_out,
    const float* __restrict__ b_out, float* __restrict__ dst)
{
  __shared__ __align__(16) short As[4*32*8];
  __shared__ __align__(16) short Bs[4*256*8];
  __shared__ float ws[5*256];
  __shared__ float s_log[4][16][5];
  int tid=threadIdx.x, lane=tid&63, w=tid>>6, quad=lane>>4, l15=lane&15;
  int g = w>>1, n0w = (w&1)*128;
  int m0 = blockIdx.x*32;
  int arow = min(m0 + (lane&31), MROWS-1);
  const short* aPtr = x2pad + rowoff[arow] + (2*w + (lane>>5))*8;
  for (int i=tid; i<5*256; i+=256) ws[i]=w_out[i];

  floatx4 acc[8];
  #pragma unroll
  for (int i=0;i<8;i++) acc[i] = (floatx4){0.f,0.f,0.f,0.f};
  for (int chunk=0; chunk<24; chunk++){
    int k0 = chunk*32;
    if (w < 2) g2l16(aPtr + k0, &As[w*64*8]);
    #pragma unroll
    for (int ng=0; ng<4; ng++)
      g2l16(w3t + (size_t)(ng*64+lane)*768 + k0 + w*8, &Bs[(w*256 + ng*64)*8]);
    __syncthreads();
    short8 af = *(const short8*)&As[(quad*32 + g*16 + l15)*8];
    #pragma unroll
    for (int nt=0; nt<8; nt++){
      short8 bf = *(const short8*)&Bs[(quad*256 + n0w + nt*16 + l15)*8];
      acc[nt] = __builtin_amdgcn_mfma_f32_16x16x32_bf16(af, bf, acc[nt], 0,0,0);
    }
    __syncthreads();
  }

  int mbase = m0 + g*16 + quad*4;
  float np_[4];
  #pragma unroll
  for (int r=0;r<4;r++) np_[r] = nonpad[min(mbase+r, MROWS-1)];
  float p[4][5];
  #pragma unroll
  for (int r=0;r<4;r++)
    #pragma unroll
    for (int o=0;o<5;o++) p[r][o]=0.f;
  #pragma unroll
  for (int nt=0; nt<8; nt++){
    int n = n0w + nt*16 + l15;
    float pb = postb[n];
    float wv[5];
    #pragma unroll
    for (int o=0;o<5;o++) wv[o]=ws[o*256+n];
    #pragma unroll
    for (int r=0;r<4;r++){
      float v = (acc[nt][r] + pb)*np_[r];
      #pragma unroll
      for (int o=0;o<5;o++) p[r][o] += v*wv[o];
    }
  }
  #pragma unroll
  for (int off=1; off<16; off<<=1)
    #pragma unroll
    for (int r=0;r<4;r++)
      #pragma unroll
      for (int o=0;o<5;o++) p[r][o]+=__shfl_xor(p[r][o],off,64);
  if (l15==0){
    #pragma unroll
    for (int r=0;r<4;r++)
      #pragma unroll
      for (int o=0;o<5;o++) s_log[w][quad*4+r][o]=p[r][o];
  }
  __syncthreads();
  if (l15==0 && (w&1)==0){
    #pragma unroll
    for (int r=0;r<4;r++){
      int m = mbase + r;
      if (m < MROWS){
        int i = quad*4+r;
        #pragma unroll
        for (int o=0;o<5;o++)
          dst[(size_t)m*5+o] = s_log[w][i][o] + s_log[w+1][i][o] + b_out[o];
      }
    }
  }
}

extern "C" void kernel_launch(void* const* d_in, const int* in_sizes, int n_in,
                              void* d_out, int out_size, void* d_ws, size_t ws_size,
                              hipStream_t stream) {
  const float* feat    = (const float*)d_in[0];
  const int*   ph_bd   = (const int*)  d_in[1];
  const float* w_attn  = (const float*)d_in[3];
  const float* b_attn  = (const float*)d_in[4];
  const float* ln1_g   = (const float*)d_in[5];
  const float* ln1_b   = (const float*)d_in[6];
  const float* conv1_w = (const float*)d_in[7];
  const float* conv1_b = (const float*)d_in[8];
  const float* conv2_w = (const float*)d_in[9];
  const float* conv2_b = (const float*)d_in[10];
  const float* ln2_g   = (const float*)d_in[11];
  const float* ln2_b   = (const float*)d_in[12];
  const float* post_w  = (const float*)d_in[13];
  const float* post_b  = (const float*)d_in[14];
  const float* w_out   = (const float*)d_in[15];
  const float* b_out   = (const float*)d_in[16];

  char* wp = (char*)d_ws;
  auto alloc = [&](size_t bytes)->void*{
    void* p = (void*)wp; wp += (bytes + 255) & ~(size_t)255; return p;
  };
  int*    seg    = (int*)   alloc((size_t)BDIM*SEGW*4);
  int*    rowoff = (int*)   alloc((size_t)MROWS*4);
  float*  x0pad  = (float*) alloc((size_t)BDIM*PADL*HDIM*4);
  __bf16* h1pad  = (__bf16*)alloc((size_t)BDIM*PADL*HDIM*2);
  __bf16* x2pad  = (__bf16*)alloc((size_t)BDIM*PADL*HDIM*2);
  float*  nonpad = (float*) alloc((size_t)MROWS*4);
  __bf16* w1t    = (__bf16*)alloc((size_t)256*768*2);
  __bf16* w2t    = (__bf16*)alloc((size_t)256*256*2);
  __bf16* w3t    = (__bf16*)alloc((size_t)256*768*2);

  k_init<<<BDIM+768, 256, 0, stream>>>(ph_bd, seg, conv1_w, conv2_w, post_w,
                                       w1t, w2t, w3t, rowoff, x0pad, h1pad, x2pad);
  k_attn<<<MROWS, 256, 0, stream>>>(feat, seg, w_attn, b_attn,
                                    ln1_g, ln1_b, x0pad, h1pad, nonpad);
  k_convblock<<<257, 256, 0, stream>>>((const short*)h1pad, rowoff, (const short*)w1t,
                                       (const short*)w2t, conv1_b, conv2_b,
                                       x0pad, nonpad, ln2_g, ln2_b, x2pad);
  k_post<<<257, 256, 0, stream>>>((const short*)x2pad, rowoff, (const short*)w3t,
                                  post_b, nonpad, w_out, b_out, (float*)d_out);
}